// Round 1
// baseline (95.139 us; speedup 1.0000x reference)
//
#include <hip/hip_runtime.h>
#include <hip/hip_bf16.h>

#define N_SIDE 14
#define N_PATCH (N_SIDE * N_SIDE)   // 196
#define D_BB 384
#define D_MODEL 512
#define BT_TOTAL 2048
#define LN_EPS 1e-5f
#define ROWS 8                       // rows per gemm block

// ---------------- Kernel 1: ROI mean pool ----------------
// grid = BT_TOTAL blocks, block = 384 threads (one per backbone channel)
__global__ __launch_bounds__(D_BB) void pool_kernel(
    const float* __restrict__ patch,   // [BT,196,384]
    const float* __restrict__ bboxes,  // [BT,4]
    float* __restrict__ pooled)        // [BT,384]
{
    const int bt = blockIdx.x;
    const int d  = threadIdx.x;

    const float bx1 = bboxes[bt * 4 + 0];
    const float by1 = bboxes[bt * 4 + 1];
    const float bx2 = bboxes[bt * 4 + 2];
    const float by2 = bboxes[bt * 4 + 3];

    // match reference exactly: clip -> trunc/ceil -> clip -> max
    int x1 = (int)fminf(fmaxf(bx1 * (float)N_SIDE, 0.f), (float)(N_SIDE - 1));
    int y1 = (int)fminf(fmaxf(by1 * (float)N_SIDE, 0.f), (float)(N_SIDE - 1));
    int x2 = (int)fminf(fmaxf(ceilf(fminf(fmaxf(bx2 * (float)N_SIDE, 0.f), (float)N_SIDE)), 1.f), (float)N_SIDE);
    int y2 = (int)fminf(fmaxf(ceilf(fminf(fmaxf(by2 * (float)N_SIDE, 0.f), (float)N_SIDE)), 1.f), (float)N_SIDE);
    x2 = max(x2, x1 + 1);
    y2 = max(y2, y1 + 1);

    const float inv_count = 1.f / (float)((y2 - y1) * (x2 - x1));

    const float* base = patch + (size_t)bt * N_PATCH * D_BB;
    float acc = 0.f;
    for (int y = y1; y < y2; ++y) {
        const float* rowp = base + (size_t)(y * N_SIDE) * D_BB;
        for (int x = x1; x < x2; ++x) {
            acc += rowp[(size_t)x * D_BB + d];
        }
    }
    pooled[(size_t)bt * D_BB + d] = acc * inv_count;
}

// ---------------- Kernel 2: GEMM (pooled @ W + b) + LayerNorm + vis blend ----------------
// grid = BT_TOTAL/ROWS blocks, block = 512 threads (one per output column)
__global__ __launch_bounds__(D_MODEL) void gemm_ln_kernel(
    const float* __restrict__ pooled,    // [BT,384]
    const float* __restrict__ W,         // [384,512]
    const float* __restrict__ bias,      // [512]
    const float* __restrict__ gamma,     // [512]
    const float* __restrict__ beta,      // [512]
    const float* __restrict__ mask_tok,  // [512]
    const float* __restrict__ vis,       // [BT]
    float* __restrict__ out)             // [BT,512]
{
    const int j  = threadIdx.x;
    const int r0 = blockIdx.x * ROWS;

    float acc[ROWS];
    const float bj = bias[j];
#pragma unroll
    for (int r = 0; r < ROWS; ++r) acc[r] = bj;

    const float* p0 = pooled + (size_t)r0 * D_BB;   // workgroup-uniform base

#pragma unroll 4
    for (int d = 0; d < D_BB; ++d) {
        const float w = W[(size_t)d * D_MODEL + j];   // coalesced across wave
#pragma unroll
        for (int r = 0; r < ROWS; ++r) {
            acc[r] = fmaf(p0[(size_t)r * D_BB + d], w, acc[r]);  // uniform addr -> s_load
        }
    }

    // ---- LayerNorm across the 512 columns (all threads of the block) ----
    __shared__ float red[8][ROWS][2];   // 8 waves
    const int wave = j >> 6;
    const int lane = j & 63;

#pragma unroll
    for (int r = 0; r < ROWS; ++r) {
        float s  = acc[r];
        float s2 = acc[r] * acc[r];
#pragma unroll
        for (int off = 32; off >= 1; off >>= 1) {
            s  += __shfl_xor(s,  off);
            s2 += __shfl_xor(s2, off);
        }
        if (lane == 0) { red[wave][r][0] = s; red[wave][r][1] = s2; }
    }
    __syncthreads();

    const float g  = gamma[j];
    const float be = beta[j];
    const float mt = mask_tok[j];

#pragma unroll
    for (int r = 0; r < ROWS; ++r) {
        float s = 0.f, s2 = 0.f;
#pragma unroll
        for (int w = 0; w < 8; ++w) { s += red[w][r][0]; s2 += red[w][r][1]; }
        const float mean = s * (1.f / (float)D_MODEL);
        const float var  = s2 * (1.f / (float)D_MODEL) - mean * mean;
        float val = (acc[r] - mean) * rsqrtf(var + LN_EPS) * g + be;
        const float v = vis[r0 + r];
        val = v * val + (1.f - v) * mt;
        out[(size_t)(r0 + r) * D_MODEL + j] = val;
    }
}

extern "C" void kernel_launch(void* const* d_in, const int* in_sizes, int n_in,
                              void* d_out, int out_size, void* d_ws, size_t ws_size,
                              hipStream_t stream) {
    const float* patch  = (const float*)d_in[0];  // patch_tokens [2048,196,384]
    const float* bboxes = (const float*)d_in[1];  // [2048,4]
    const float* vis    = (const float*)d_in[2];  // [2048]
    // d_in[3] = B, d_in[4] = T (scalars, unused)
    const float* W      = (const float*)d_in[5];  // [384,512]
    const float* bias   = (const float*)d_in[6];  // [512]
    const float* gamma  = (const float*)d_in[7];  // [512]
    const float* beta   = (const float*)d_in[8];  // [512]
    const float* mtok   = (const float*)d_in[9];  // [1,512]

    float* pooled = (float*)d_ws;                 // [2048,384] = 3 MB scratch
    float* out    = (float*)d_out;

    pool_kernel<<<BT_TOTAL, D_BB, 0, stream>>>(patch, bboxes, pooled);
    gemm_ln_kernel<<<BT_TOTAL / ROWS, D_MODEL, 0, stream>>>(
        pooled, W, bias, gamma, beta, mtok, vis, out);
}

// Round 3
// 45.828 us; speedup vs baseline: 2.0760x; 2.0760x over previous
//
#include <hip/hip_runtime.h>
#include <hip/hip_bf16.h>

#define N_SIDE 14
#define N_PATCH (N_SIDE * N_SIDE)   // 196
#define D_BB 384
#define DQ_BB (D_BB / 4)             // 96 float4 per cell
#define D_MODEL 512
#define CQ (D_MODEL / 4)             // 128 col-quads
#define BT_TOTAL 2048
#define LN_EPS 1e-5f
#define ROWS 8                       // rows per gemm block
#define KP 4                         // K partitions per gemm block
#define KCHUNK (D_BB / KP)           // 96

__device__ __forceinline__ void fma4(float4& a, float s, const float4& wv) {
    a.x = fmaf(s, wv.x, a.x);
    a.y = fmaf(s, wv.y, a.y);
    a.z = fmaf(s, wv.z, a.z);
    a.w = fmaf(s, wv.w, a.w);
}

// ---------------- Kernel 1: ROI mean pool ----------------
// grid = BT_TOTAL, block = 384 threads = 96 channel-quads x 4 cell-groups
__global__ __launch_bounds__(384) void pool_kernel(
    const float* __restrict__ patch,   // [BT,196,384]
    const float* __restrict__ bboxes,  // [BT,4]
    float* __restrict__ pooled)        // [BT,384]
{
    const int bt = blockIdx.x;
    const int t  = threadIdx.x;
    const int qd = t % DQ_BB;   // channel quad 0..95
    const int g  = t / DQ_BB;   // cell group 0..3

    const float bx1 = bboxes[bt * 4 + 0];
    const float by1 = bboxes[bt * 4 + 1];
    const float bx2 = bboxes[bt * 4 + 2];
    const float by2 = bboxes[bt * 4 + 3];

    // match reference exactly: clip -> trunc/ceil -> clip -> max
    int x1 = (int)fminf(fmaxf(bx1 * (float)N_SIDE, 0.f), (float)(N_SIDE - 1));
    int y1 = (int)fminf(fmaxf(by1 * (float)N_SIDE, 0.f), (float)(N_SIDE - 1));
    int x2 = (int)fminf(fmaxf(ceilf(fminf(fmaxf(bx2 * (float)N_SIDE, 0.f), (float)N_SIDE)), 1.f), (float)N_SIDE);
    int y2 = (int)fminf(fmaxf(ceilf(fminf(fmaxf(by2 * (float)N_SIDE, 0.f), (float)N_SIDE)), 1.f), (float)N_SIDE);
    x2 = max(x2, x1 + 1);
    y2 = max(y2, y1 + 1);

    const float inv_count = 1.f / (float)((y2 - y1) * (x2 - x1));

    const float4* base = (const float4*)(patch + (size_t)bt * N_PATCH * D_BB);
    float4 acc = make_float4(0.f, 0.f, 0.f, 0.f);

    for (int y = y1; y < y2; ++y) {
        const float4* rowp = base + (size_t)(y * N_SIDE + x1) * DQ_BB;
        const int wd = x2 - x1;
        for (int c = g; c < wd; c += 4) {
            const float4 v = rowp[(size_t)c * DQ_BB + qd];
            acc.x += v.x; acc.y += v.y; acc.z += v.z; acc.w += v.w;
        }
    }

    __shared__ float4 part[4][DQ_BB];   // 6 KB
    part[g][qd] = acc;
    __syncthreads();

    if (t < DQ_BB) {
        float4 s = part[0][t];
        const float4 s1 = part[1][t];
        const float4 s2 = part[2][t];
        const float4 s3 = part[3][t];
        s.x = (s.x + s1.x + s2.x + s3.x) * inv_count;
        s.y = (s.y + s1.y + s2.y + s3.y) * inv_count;
        s.z = (s.z + s1.z + s2.z + s3.z) * inv_count;
        s.w = (s.w + s1.w + s2.w + s3.w) * inv_count;
        ((float4*)pooled)[(size_t)bt * DQ_BB + t] = s;
    }
}

// ---------------- Kernel 2: GEMM (pooled @ W + b) + LayerNorm + vis blend ----------------
// grid = BT_TOTAL/ROWS = 256, block = 512 = 128 col-quads x 4 K-partitions
__global__ __launch_bounds__(512) void gemm_ln_kernel(
    const float* __restrict__ pooled,    // [BT,384]
    const float* __restrict__ W,         // [384,512]
    const float* __restrict__ bias,      // [512]
    const float* __restrict__ gamma,     // [512]
    const float* __restrict__ beta,      // [512]
    const float* __restrict__ mask_tok,  // [512]
    const float* __restrict__ vis,       // [BT]
    float* __restrict__ out)             // [BT,512]
{
    const int tid  = threadIdx.x;
    const int part = tid >> 7;       // 0..3 (K partition)
    const int jq   = tid & 127;      // col quad 0..127
    const int r0   = blockIdx.x * ROWS;

    __shared__ float sp[ROWS][D_BB];            // 12 KB: the 8 pooled rows
    __shared__ float red[KP - 1][32][CQ];       // 48 KB, element-major: conflict-free
    __shared__ float lnred[2][ROWS][2];

    // ---- stage pooled rows into LDS (vectorized, coalesced) ----
    {
        const float4* p4  = (const float4*)(pooled + (size_t)r0 * D_BB);
        float4*       sp4 = (float4*)sp;
        for (int i = tid; i < ROWS * DQ_BB; i += 512) sp4[i] = p4[i];
    }
    __syncthreads();

    const float4* Wq = (const float4*)W;   // [384][128] float4
    float4 acc[ROWS];
#pragma unroll
    for (int r = 0; r < ROWS; ++r) acc[r] = make_float4(0.f, 0.f, 0.f, 0.f);

    const int dbase = part * KCHUNK;
#pragma unroll 2
    for (int i = 0; i < KCHUNK / 4; ++i) {
        const int d = dbase + i * 4;
        const float4 w0 = Wq[(size_t)(d + 0) * CQ + jq];
        const float4 w1 = Wq[(size_t)(d + 1) * CQ + jq];
        const float4 w2 = Wq[(size_t)(d + 2) * CQ + jq];
        const float4 w3 = Wq[(size_t)(d + 3) * CQ + jq];
#pragma unroll
        for (int r = 0; r < ROWS; ++r) {
            const float4 a = *(const float4*)&sp[r][d];   // LDS broadcast
            fma4(acc[r], a.x, w0);
            fma4(acc[r], a.y, w1);
            fma4(acc[r], a.z, w2);
            fma4(acc[r], a.w, w3);
        }
    }

    // ---- cross-partition reduction via LDS ----
    if (part != 0) {
#pragma unroll
        for (int r = 0; r < ROWS; ++r) {
            red[part - 1][r * 4 + 0][jq] = acc[r].x;
            red[part - 1][r * 4 + 1][jq] = acc[r].y;
            red[part - 1][r * 4 + 2][jq] = acc[r].z;
            red[part - 1][r * 4 + 3][jq] = acc[r].w;
        }
    }
    __syncthreads();

    if (part == 0) {
#pragma unroll
        for (int p = 0; p < KP - 1; ++p) {
#pragma unroll
            for (int r = 0; r < ROWS; ++r) {
                acc[r].x += red[p][r * 4 + 0][jq];
                acc[r].y += red[p][r * 4 + 1][jq];
                acc[r].z += red[p][r * 4 + 2][jq];
                acc[r].w += red[p][r * 4 + 3][jq];
            }
        }
        const float4 bj = ((const float4*)bias)[jq];
#pragma unroll
        for (int r = 0; r < ROWS; ++r) {
            acc[r].x += bj.x; acc[r].y += bj.y; acc[r].z += bj.z; acc[r].w += bj.w;
        }

        // ---- LN partial sums across 128 threads (2 waves) ----
        const int lane = tid & 63;
        const int wv   = tid >> 6;   // 0 or 1
#pragma unroll
        for (int r = 0; r < ROWS; ++r) {
            float s  = acc[r].x + acc[r].y + acc[r].z + acc[r].w;
            float s2 = acc[r].x * acc[r].x + acc[r].y * acc[r].y +
                       acc[r].z * acc[r].z + acc[r].w * acc[r].w;
#pragma unroll
            for (int off = 32; off >= 1; off >>= 1) {
                s  += __shfl_xor(s,  off);
                s2 += __shfl_xor(s2, off);
            }
            if (lane == 0) { lnred[wv][r][0] = s; lnred[wv][r][1] = s2; }
        }
    }
    __syncthreads();

    if (part == 0) {
        const float4 g4 = ((const float4*)gamma)[jq];
        const float4 b4 = ((const float4*)beta)[jq];
        const float4 m4 = ((const float4*)mask_tok)[jq];
#pragma unroll
        for (int r = 0; r < ROWS; ++r) {
            const float s    = lnred[0][r][0] + lnred[1][r][0];
            const float s2   = lnred[0][r][1] + lnred[1][r][1];
            const float mean = s * (1.f / (float)D_MODEL);
            const float var  = s2 * (1.f / (float)D_MODEL) - mean * mean;
            const float rstd = rsqrtf(var + LN_EPS);
            const float v    = vis[r0 + r];
            const float iv   = 1.f - v;
            float4 o;
            o.x = v * ((acc[r].x - mean) * rstd * g4.x + b4.x) + iv * m4.x;
            o.y = v * ((acc[r].y - mean) * rstd * g4.y + b4.y) + iv * m4.y;
            o.z = v * ((acc[r].z - mean) * rstd * g4.z + b4.z) + iv * m4.z;
            o.w = v * ((acc[r].w - mean) * rstd * g4.w + b4.w) + iv * m4.w;
            ((float4*)out)[(size_t)(r0 + r) * CQ + jq] = o;
        }
    }
}

extern "C" void kernel_launch(void* const* d_in, const int* in_sizes, int n_in,
                              void* d_out, int out_size, void* d_ws, size_t ws_size,
                              hipStream_t stream) {
    const float* patch  = (const float*)d_in[0];  // [2048,196,384]
    const float* bboxes = (const float*)d_in[1];  // [2048,4]
    const float* vis    = (const float*)d_in[2];  // [2048]
    // d_in[3] = B, d_in[4] = T (scalars, unused)
    const float* W      = (const float*)d_in[5];  // [384,512]
    const float* bias   = (const float*)d_in[6];  // [512]
    const float* gamma  = (const float*)d_in[7];  // [512]
    const float* beta   = (const float*)d_in[8];  // [512]
    const float* mtok   = (const float*)d_in[9];  // [1,512]

    float* pooled = (float*)d_ws;                 // [2048,384] = 3 MB scratch
    float* out    = (float*)d_out;

    pool_kernel<<<BT_TOTAL, 384, 0, stream>>>(patch, bboxes, pooled);
    gemm_ln_kernel<<<BT_TOTAL / ROWS, 512, 0, stream>>>(
        pooled, W, bias, gamma, beta, mtok, vis, out);
}

// Round 4
// 37.676 us; speedup vs baseline: 2.5252x; 1.2164x over previous
//
#include <hip/hip_runtime.h>
#include <hip/hip_bf16.h>

#define N_SIDE 14
#define N_PATCH (N_SIDE * N_SIDE)   // 196
#define D_BB 384
#define DQ_BB (D_BB / 4)             // 96 float4 per cell
#define D_MODEL 512
#define CQ (D_MODEL / 4)             // 128 col-quads
#define BT_TOTAL 2048
#define LN_EPS 1e-5f
#define ROWS 8                       // rows per gemm block
#define KP 4                         // K partitions per gemm block
#define KCHUNK (D_BB / KP)           // 96
#define GROUPS 8                     // cell groups in pool kernel

__device__ __forceinline__ void fma4(float4& a, float s, const float4& wv) {
    a.x = fmaf(s, wv.x, a.x);
    a.y = fmaf(s, wv.y, a.y);
    a.z = fmaf(s, wv.z, a.z);
    a.w = fmaf(s, wv.w, a.w);
}

// ---------------- Kernel 1: ROI mean pool ----------------
// grid = BT_TOTAL, block = 768 threads = 96 channel-quads x 8 cell-groups.
// Region cells flattened to 1-D; 4-deep manual pipeline for MLP.
__global__ __launch_bounds__(768) void pool_kernel(
    const float* __restrict__ patch,   // [BT,196,384]
    const float* __restrict__ bboxes,  // [BT,4]
    float* __restrict__ pooled)        // [BT,384]
{
    const int bt = blockIdx.x;
    const int t  = threadIdx.x;
    const int qd = t % DQ_BB;   // channel quad 0..95
    const int g  = t / DQ_BB;   // cell group 0..7

    const float bx1 = bboxes[bt * 4 + 0];
    const float by1 = bboxes[bt * 4 + 1];
    const float bx2 = bboxes[bt * 4 + 2];
    const float by2 = bboxes[bt * 4 + 3];

    // match reference exactly: clip -> trunc/ceil -> clip -> max
    int x1 = (int)fminf(fmaxf(bx1 * (float)N_SIDE, 0.f), (float)(N_SIDE - 1));
    int y1 = (int)fminf(fmaxf(by1 * (float)N_SIDE, 0.f), (float)(N_SIDE - 1));
    int x2 = (int)fminf(fmaxf(ceilf(fminf(fmaxf(bx2 * (float)N_SIDE, 0.f), (float)N_SIDE)), 1.f), (float)N_SIDE);
    int y2 = (int)fminf(fmaxf(ceilf(fminf(fmaxf(by2 * (float)N_SIDE, 0.f), (float)N_SIDE)), 1.f), (float)N_SIDE);
    x2 = max(x2, x1 + 1);
    y2 = max(y2, y1 + 1);

    const int wd = x2 - x1;
    const int ht = y2 - y1;
    const int total = wd * ht;
    const float inv_count = 1.f / (float)total;
    const float inv_wd = 1.f / (float)wd;
    const int cell0 = y1 * N_SIDE + x1;   // top-left cell

    const float4* __restrict__ base = (const float4*)patch + (size_t)bt * N_PATCH * DQ_BB + qd;

    // flattened cell c -> grid offset (exact: (c+0.5)/wd is >=0.5/14 from any integer)
    auto cell_off = [&](int c) -> size_t {
        const int y = (int)(((float)c + 0.5f) * inv_wd);
        const int x = c - y * wd;
        return (size_t)(cell0 + y * N_SIDE + x) * DQ_BB;
    };

    float4 acc = make_float4(0.f, 0.f, 0.f, 0.f);
    int c = g;
    // 4-deep: issue 4 independent loads, then accumulate
    for (; c + 3 * GROUPS < total; c += 4 * GROUPS) {
        const float4 v0 = base[cell_off(c)];
        const float4 v1 = base[cell_off(c + GROUPS)];
        const float4 v2 = base[cell_off(c + 2 * GROUPS)];
        const float4 v3 = base[cell_off(c + 3 * GROUPS)];
        acc.x += (v0.x + v1.x) + (v2.x + v3.x);
        acc.y += (v0.y + v1.y) + (v2.y + v3.y);
        acc.z += (v0.z + v1.z) + (v2.z + v3.z);
        acc.w += (v0.w + v1.w) + (v2.w + v3.w);
    }
    for (; c < total; c += GROUPS) {
        const float4 v = base[cell_off(c)];
        acc.x += v.x; acc.y += v.y; acc.z += v.z; acc.w += v.w;
    }

    __shared__ float4 part[GROUPS][DQ_BB];   // 12 KB
    part[g][qd] = acc;
    __syncthreads();

    if (t < DQ_BB) {
        float4 s = part[0][t];
#pragma unroll
        for (int p = 1; p < GROUPS; ++p) {
            const float4 v = part[p][t];
            s.x += v.x; s.y += v.y; s.z += v.z; s.w += v.w;
        }
        s.x *= inv_count; s.y *= inv_count; s.z *= inv_count; s.w *= inv_count;
        ((float4*)pooled)[(size_t)bt * DQ_BB + t] = s;
    }
}

// ---------------- Kernel 2: GEMM (pooled @ W + b) + LayerNorm + vis blend ----------------
// grid = BT_TOTAL/ROWS = 256, block = 512 = 128 col-quads x 4 K-partitions
__global__ __launch_bounds__(512) void gemm_ln_kernel(
    const float* __restrict__ pooled,    // [BT,384]
    const float* __restrict__ W,         // [384,512]
    const float* __restrict__ bias,      // [512]
    const float* __restrict__ gamma,     // [512]
    const float* __restrict__ beta,      // [512]
    const float* __restrict__ mask_tok,  // [512]
    const float* __restrict__ vis,       // [BT]
    float* __restrict__ out)             // [BT,512]
{
    const int tid  = threadIdx.x;
    const int part = tid >> 7;       // 0..3 (K partition)
    const int jq   = tid & 127;      // col quad 0..127
    const int r0   = blockIdx.x * ROWS;

    __shared__ float sp[ROWS][D_BB];            // 12 KB: the 8 pooled rows
    __shared__ float red[KP - 1][32][CQ];       // 48 KB, element-major: conflict-free
    __shared__ float lnred[2][ROWS][2];

    // ---- stage pooled rows into LDS (vectorized, coalesced) ----
    {
        const float4* p4  = (const float4*)(pooled + (size_t)r0 * D_BB);
        float4*       sp4 = (float4*)sp;
        for (int i = tid; i < ROWS * DQ_BB; i += 512) sp4[i] = p4[i];
    }
    __syncthreads();

    const float4* Wq = (const float4*)W;   // [384][128] float4
    float4 acc[ROWS];
#pragma unroll
    for (int r = 0; r < ROWS; ++r) acc[r] = make_float4(0.f, 0.f, 0.f, 0.f);

    const int dbase = part * KCHUNK;
#pragma unroll 2
    for (int i = 0; i < KCHUNK / 4; ++i) {
        const int d = dbase + i * 4;
        const float4 w0 = Wq[(size_t)(d + 0) * CQ + jq];
        const float4 w1 = Wq[(size_t)(d + 1) * CQ + jq];
        const float4 w2 = Wq[(size_t)(d + 2) * CQ + jq];
        const float4 w3 = Wq[(size_t)(d + 3) * CQ + jq];
#pragma unroll
        for (int r = 0; r < ROWS; ++r) {
            const float4 a = *(const float4*)&sp[r][d];   // LDS broadcast
            fma4(acc[r], a.x, w0);
            fma4(acc[r], a.y, w1);
            fma4(acc[r], a.z, w2);
            fma4(acc[r], a.w, w3);
        }
    }

    // ---- cross-partition reduction via LDS ----
    if (part != 0) {
#pragma unroll
        for (int r = 0; r < ROWS; ++r) {
            red[part - 1][r * 4 + 0][jq] = acc[r].x;
            red[part - 1][r * 4 + 1][jq] = acc[r].y;
            red[part - 1][r * 4 + 2][jq] = acc[r].z;
            red[part - 1][r * 4 + 3][jq] = acc[r].w;
        }
    }
    __syncthreads();

    if (part == 0) {
#pragma unroll
        for (int p = 0; p < KP - 1; ++p) {
#pragma unroll
            for (int r = 0; r < ROWS; ++r) {
                acc[r].x += red[p][r * 4 + 0][jq];
                acc[r].y += red[p][r * 4 + 1][jq];
                acc[r].z += red[p][r * 4 + 2][jq];
                acc[r].w += red[p][r * 4 + 3][jq];
            }
        }
        const float4 bj = ((const float4*)bias)[jq];
#pragma unroll
        for (int r = 0; r < ROWS; ++r) {
            acc[r].x += bj.x; acc[r].y += bj.y; acc[r].z += bj.z; acc[r].w += bj.w;
        }

        // ---- LN partial sums across 128 threads (2 waves) ----
        const int lane = tid & 63;
        const int wv   = tid >> 6;   // 0 or 1
#pragma unroll
        for (int r = 0; r < ROWS; ++r) {
            float s  = acc[r].x + acc[r].y + acc[r].z + acc[r].w;
            float s2 = acc[r].x * acc[r].x + acc[r].y * acc[r].y +
                       acc[r].z * acc[r].z + acc[r].w * acc[r].w;
#pragma unroll
            for (int off = 32; off >= 1; off >>= 1) {
                s  += __shfl_xor(s,  off);
                s2 += __shfl_xor(s2, off);
            }
            if (lane == 0) { lnred[wv][r][0] = s; lnred[wv][r][1] = s2; }
        }
    }
    __syncthreads();

    if (part == 0) {
        const float4 g4 = ((const float4*)gamma)[jq];
        const float4 b4 = ((const float4*)beta)[jq];
        const float4 m4 = ((const float4*)mask_tok)[jq];
#pragma unroll
        for (int r = 0; r < ROWS; ++r) {
            const float s    = lnred[0][r][0] + lnred[1][r][0];
            const float s2   = lnred[0][r][1] + lnred[1][r][1];
            const float mean = s * (1.f / (float)D_MODEL);
            const float var  = s2 * (1.f / (float)D_MODEL) - mean * mean;
            const float rstd = rsqrtf(var + LN_EPS);
            const float v    = vis[r0 + r];
            const float iv   = 1.f - v;
            float4 o;
            o.x = v * ((acc[r].x - mean) * rstd * g4.x + b4.x) + iv * m4.x;
            o.y = v * ((acc[r].y - mean) * rstd * g4.y + b4.y) + iv * m4.y;
            o.z = v * ((acc[r].z - mean) * rstd * g4.z + b4.z) + iv * m4.z;
            o.w = v * ((acc[r].w - mean) * rstd * g4.w + b4.w) + iv * m4.w;
            ((float4*)out)[(size_t)(r0 + r) * CQ + jq] = o;
        }
    }
}

extern "C" void kernel_launch(void* const* d_in, const int* in_sizes, int n_in,
                              void* d_out, int out_size, void* d_ws, size_t ws_size,
                              hipStream_t stream) {
    const float* patch  = (const float*)d_in[0];  // [2048,196,384]
    const float* bboxes = (const float*)d_in[1];  // [2048,4]
    const float* vis    = (const float*)d_in[2];  // [2048]
    // d_in[3] = B, d_in[4] = T (scalars, unused)
    const float* W      = (const float*)d_in[5];  // [384,512]
    const float* bias   = (const float*)d_in[6];  // [512]
    const float* gamma  = (const float*)d_in[7];  // [512]
    const float* beta   = (const float*)d_in[8];  // [512]
    const float* mtok   = (const float*)d_in[9];  // [1,512]

    float* pooled = (float*)d_ws;                 // [2048,384] = 3 MB scratch
    float* out    = (float*)d_out;

    pool_kernel<<<BT_TOTAL, 768, 0, stream>>>(patch, bboxes, pooled);
    gemm_ln_kernel<<<BT_TOTAL / ROWS, 512, 0, stream>>>(
        pooled, W, bias, gamma, beta, mtok, vis, out);
}